// Round 16
// baseline (44.384 us; speedup 1.0000x reference)
//
#include <hip/hip_runtime.h>

#define N     384
#define BSZ   192
#define NM1   383
#define D     1024
#define DELTA 0.1f
#define NT    24                    // 16-row panels / tiles per dim
#define NTILES (NT * (NT + 1) / 2)  // 300 upper-tri tiles
#define PANEL 16384                 // halfs per panel: 16 rows * 1024

typedef __attribute__((ext_vector_type(8))) short bf16x8;
typedef __attribute__((ext_vector_type(8))) unsigned short u16x8;
typedef __attribute__((ext_vector_type(4))) float f32x4;

__device__ __forceinline__ const float* feat_row(const float* feats, int i) {
    // features laid out [192][2][1024]; logical row i of the [384,1024] concat
    int b = (i < BSZ) ? i : (i - BSZ);
    int s = (i < BSZ) ? 0 : 1;
    return feats + (size_t)(b * 2 + s) * D;
}

__device__ __forceinline__ unsigned short f2bf(float x) {  // RNE f32->bf16
    unsigned u = __builtin_bit_cast(unsigned, x);
    u = (u + 0x7FFFu + ((u >> 16) & 1u)) >> 16;
    return (unsigned short)u;
}
__device__ __forceinline__ float bf2f(unsigned short h) {
    unsigned u = ((unsigned)h) << 16;
    return __builtin_bit_cast(float, u);
}

// Panel-cooperative cvt: block = (panel p, k-chunk c of 32 k). Lane l handles
// row p*16+(l&15), k8 = c*4+(l>>4): reads 32B, writes ONE u16x8 (16B); the 16
// lanes of a k8-group write 256B contiguous -> fully coalesced fragment-major.
// sq via global f32 atomics (buffer memset to 0 before launch).
__global__ __launch_bounds__(64) void k_cvt(const float* __restrict__ feats,
                                            unsigned short* __restrict__ Ht,
                                            unsigned short* __restrict__ Lt,
                                            float* __restrict__ sq) {
    const int p = blockIdx.x >> 5, c = blockIdx.x & 31;
    const int l = threadIdx.x;
    const int row = p * 16 + (l & 15);
    const int k8  = c * 4 + (l >> 4);
    const float* fr = feat_row(feats, row) + k8 * 8;
    const float4 va = *(const float4*)fr;
    const float4 vb = *(const float4*)(fr + 4);
    float p2 = 0.f;
    p2 = fmaf(va.x, va.x, p2); p2 = fmaf(va.y, va.y, p2);
    p2 = fmaf(va.z, va.z, p2); p2 = fmaf(va.w, va.w, p2);
    p2 = fmaf(vb.x, vb.x, p2); p2 = fmaf(vb.y, vb.y, p2);
    p2 = fmaf(vb.z, vb.z, p2); p2 = fmaf(vb.w, vb.w, p2);
    u16x8 hv, lv;
    hv[0] = f2bf(va.x); lv[0] = f2bf(va.x - bf2f(hv[0]));
    hv[1] = f2bf(va.y); lv[1] = f2bf(va.y - bf2f(hv[1]));
    hv[2] = f2bf(va.z); lv[2] = f2bf(va.z - bf2f(hv[2]));
    hv[3] = f2bf(va.w); lv[3] = f2bf(va.w - bf2f(hv[3]));
    hv[4] = f2bf(vb.x); lv[4] = f2bf(vb.x - bf2f(hv[4]));
    hv[5] = f2bf(vb.y); lv[5] = f2bf(vb.y - bf2f(hv[5]));
    hv[6] = f2bf(vb.z); lv[6] = f2bf(vb.z - bf2f(hv[6]));
    hv[7] = f2bf(vb.w); lv[7] = f2bf(vb.w - bf2f(hv[7]));
    const size_t o = (size_t)p * PANEL + (size_t)k8 * 128 + (l & 15) * 8;
    *(u16x8*)(Ht + o) = hv;
    *(u16x8*)(Lt + o) = lv;
    p2 += __shfl_xor(p2, 16);
    p2 += __shfl_xor(p2, 32);
    if (l < 16) atomicAdd(&sq[row], p2);
}

// Gram via MFMA on fragment-major H/L (unchanged; measured ~2.9us in R11).
__global__ __launch_bounds__(256) void k_gram(const unsigned short* __restrict__ Ht,
                                              const unsigned short* __restrict__ Lt,
                                              const float* __restrict__ sq,
                                              float* __restrict__ z) {
    int t = blockIdx.x, bi = 0;
    while (t >= NT - bi) { t -= NT - bi; ++bi; }
    const int bj = bi + t;
    const bool diag = (bi == bj);

    const int tid = threadIdx.x;
    const int lane = tid & 63, wv = tid >> 6;

    const size_t aBase = (size_t)bi * PANEL + (size_t)(wv * 32 + (lane >> 4)) * 128
                       + (size_t)(lane & 15) * 8;
    const size_t bBase = (size_t)bj * PANEL + (size_t)(wv * 32 + (lane >> 4)) * 128
                       + (size_t)(lane & 15) * 8;

    f32x4 aHH = {0.f,0.f,0.f,0.f}, aHL = {0.f,0.f,0.f,0.f}, aLH = {0.f,0.f,0.f,0.f};
#pragma unroll
    for (int s = 0; s < 8; ++s) {
        bf16x8 aH = *(const bf16x8*)(Ht + aBase + s * 512);
        bf16x8 aL = *(const bf16x8*)(Lt + aBase + s * 512);
        bf16x8 bH = *(const bf16x8*)(Ht + bBase + s * 512);
        bf16x8 bL = *(const bf16x8*)(Lt + bBase + s * 512);
        aHH = __builtin_amdgcn_mfma_f32_16x16x32_bf16(aH, bH, aHH, 0, 0, 0);
        aHL = __builtin_amdgcn_mfma_f32_16x16x32_bf16(aH, bL, aHL, 0, 0, 0);
        aLH = __builtin_amdgcn_mfma_f32_16x16x32_bf16(aL, bH, aLH, 0, 0, 0);
    }
    __shared__ f32x4 red[4][64];
    red[wv][lane] = aHH + aHL + aLH;
    __syncthreads();
    const int ls = tid & 63, r = tid >> 6;
    float g = red[0][ls][r] + red[1][ls][r] + red[2][ls][r] + red[3][ls][r];
    // C/D layout (verified): col = lane&15, row = (lane>>4)*4 + reg
    const int jj = bj * 16 + (ls & 15);
    const int ii = bi * 16 + ((ls >> 4) << 2) + r;
    if (ii != jj && (!diag || ii < jj)) {
        float sd = fmaxf(sq[ii] + sq[jj] - 2.f * g, 0.f);
        float v  = sqrtf(sd);
        z[ii * NM1 + (jj < ii ? jj : jj - 1)] = v;
        z[jj * NM1 + (ii < jj ? ii : ii - 1)] = v;
    }
}

// ONE WAVE per half-row (768 blocks = 3/CU exactly). Wave-synchronous counting
// sort (duplicated across the row's 2 blocks), then sweep with 3 k-slots/lane:
// one float4 LDS broadcast feeds 2 j x 192 k-slots -> 6x fewer LDS ops and
// perfect CU load balance vs the 512-thread version.
__global__ __launch_bounds__(64) void k_main(const float* __restrict__ z,
                                             const int* __restrict__ labels,
                                             float* __restrict__ partial) {
    const int b = blockIdx.x;
    const int i = b >> 1, h = b & 1;
    const int tid = threadIdx.x;
    __shared__ float zbuf[NM1];
    __shared__ unsigned char yrow[NM1];
    __shared__ int cnt[64], startv[64], cur[64];
    __shared__ float rankd[64];
    __shared__ float2 zr[N];      // sorted (z, rank*DELTA); slot 383 = (0,0)
    __shared__ unsigned grs[N];   // lo | hi<<9 per sorted slot

    cnt[tid] = 0;
    for (int k = tid; k < NM1; k += 64) zbuf[k] = z[i * NM1 + k];
    __syncthreads();
    const int li = labels[(i < BSZ) ? i : (i - BSZ)];
    for (int k = tid; k < NM1; k += 64) {
        int col = k + (k >= i ? 1 : 0);
        int ya  = abs(li - labels[(col < BSZ) ? col : (col - BSZ)]);
        yrow[k] = (unsigned char)ya;
        atomicAdd(&cnt[ya], 1);
    }
    __syncthreads();
    {   // parallel exclusive scans (counts and nonzero-count) over 64 lanes
        const int c  = cnt[tid];
        const int nz = (c > 0) ? 1 : 0;
        int sc = c, sn = nz;
#pragma unroll
        for (int d = 1; d < 64; d <<= 1) {
            int tc = __shfl_up(sc, d);
            int tn = __shfl_up(sn, d);
            if (tid >= d) { sc += tc; sn += tn; }
        }
        startv[tid] = sc - c;
        cur[tid]    = sc - c;
        rankd[tid]  = (float)(sn - nz) * DELTA;
    }
    __syncthreads();
    for (int k = tid; k < NM1; k += 64) {
        int ya  = yrow[k];
        int pos = atomicAdd(&cur[ya], 1);
        zr[pos]  = make_float2(zbuf[k], rankd[ya]);
        grs[pos] = (unsigned)startv[ya] | ((unsigned)(startv[ya] + cnt[ya]) << 9);
    }
    if (tid == 0) { zr[NM1] = make_float2(0.f, 0.f); grs[NM1] = 0u; }
    __syncthreads();

    // 3 register k-slots per lane; slot 383 is the pad (only h=1, tid=63)
    const int base = h * 192 + tid;
    const float2 A = zr[base], B = zr[base + 64], C = zr[base + 128];
    const bool v2 = !(h == 1 && tid == 63);

    float a0 = 0.f, a1 = 0.f, a2 = 0.f;
#define PP(qx, qy) do { \
        float t0 = fabsf(A.x - (qx)) - fabsf(A.y - (qy)); a0 = fmaf(t0, t0, a0); \
        float t1 = fabsf(B.x - (qx)) - fabsf(B.y - (qy)); a1 = fmaf(t1, t1, a1); \
        float t2 = fabsf(C.x - (qx)) - fabsf(C.y - (qy)); a2 = fmaf(t2, t2, a2); \
    } while (0)
    for (int j = 0; j < N; j += 4) {       // 384 incl pad-j; 2 b128 per iter
        float4 qa = *(const float4*)&zr[j];
        float4 qb = *(const float4*)&zr[j + 2];
        PP(qa.x, qa.y); PP(qa.z, qa.w);
        PP(qb.x, qb.y); PP(qb.z, qb.w);
    }
#undef PP
    {   // remove pad-j contribution: (|zk-0|-|rk-0|)^2 = (zk-rk)^2 per slot
        float t;
        t = A.x - A.y; a0 = fmaf(-t, t, a0);
        t = B.x - B.y; a1 = fmaf(-t, t, a1);
        t = C.x - C.y; a2 = fmaf(-t, t, a2);
    }
    if (!v2) a2 = 0.f;

    // correction over same-y pairs, anchored at this block's slots
    float cs = 0.f;
#pragma unroll
    for (int s = 0; s < 3; ++s) {
        const int jj = base + s * 64;
        if (jj < NM1) {
            const float    zj = zr[jj].x;
            const unsigned g  = grs[jj];
            const int lo = g & 0x1FF;
            const int hi = (g >> 9) & 0x1FF;
            for (int k = lo; k < hi; ++k) {
                float a = fabsf(zr[k].x - zj);
                cs += a * __builtin_amdgcn_rcpf(1.f + __expf(DELTA - a)) - a * a;
            }
        }
    }

    float sum = a0 + a1 + a2 + cs;
#pragma unroll
    for (int off = 32; off; off >>= 1) sum += __shfl_xor(sum, off);
    if (tid == 0) partial[b] = sum;
}

__global__ __launch_bounds__(512) void k_fin(const float* __restrict__ partial,
                                             float* __restrict__ out) {
    const int tid = threadIdx.x;
    double s = (double)partial[tid] + (double)partial[tid + 256];
    if (tid >= 256) s = 0.0;
    // tid<256 covers 512 entries? No: use plain loop for clarity/correctness.
    s = 0.0;
    for (int t = tid; t < 2 * N; t += 512) s += (double)partial[t];
#pragma unroll
    for (int off = 32; off; off >>= 1) s += __shfl_xor(s, off);
    __shared__ double dp[8];
    if ((tid & 63) == 0) dp[tid >> 6] = s;
    __syncthreads();
    if (tid == 0) {
        double ds = 0.0;
#pragma unroll
        for (int w = 0; w < 8; ++w) ds += dp[w];
        const double M = (double)N * (double)NM1 * (double)NM1;
        out[0] = (float)(ds / M);
    }
}

extern "C" void kernel_launch(void* const* d_in, const int* in_sizes, int n_in,
                              void* d_out, int out_size, void* d_ws, size_t ws_size,
                              hipStream_t stream) {
    const float* feats  = (const float*)d_in[0];
    const int*   labels = (const int*)d_in[1];
    float*       out    = (float*)d_out;

    // ws layout (~2.2 MB total):
    char* ws = (char*)d_ws;
    float*          sq      = (float*)ws;                          // 1536 B
    float*          partial = (float*)(ws + 4096);                 // 3072 B
    unsigned short* Ht      = (unsigned short*)(ws + 16384);       // 768 KiB
    unsigned short* Lt      = (unsigned short*)(ws + 16384 + 786432);        // 768 KiB
    float*          z       = (float*)(ws + 16384 + 2 * 786432);   // 588 KiB

    hipMemsetAsync(sq, 0, N * sizeof(float), stream);
    k_cvt <<<NT * 32, 64, 0, stream>>>(feats, Ht, Lt, sq);
    k_gram<<<NTILES, 256, 0, stream>>>(Ht, Lt, sq, z);
    k_main<<<2 * N, 64, 0, stream>>>(z, labels, partial);
    k_fin <<<1, 512, 0, stream>>>(partial, out);
}

// Round 17
// 33.012 us; speedup vs baseline: 1.3445x; 1.3445x over previous
//
#include <hip/hip_runtime.h>

#define N     384
#define BSZ   192
#define NM1   383
#define D     1024
#define DELTA 0.1f
#define NT    24                    // 16-row panels / tiles per dim
#define NTILES (NT * (NT + 1) / 2)  // 300 upper-tri tiles
#define PANEL 16384                 // halfs per panel: 16 rows * 1024

typedef __attribute__((ext_vector_type(8))) short bf16x8;
typedef __attribute__((ext_vector_type(8))) unsigned short u16x8;
typedef __attribute__((ext_vector_type(4))) float f32x4;

__device__ __forceinline__ const float* feat_row(const float* feats, int i) {
    // features laid out [192][2][1024]; logical row i of the [384,1024] concat
    int b = (i < BSZ) ? i : (i - BSZ);
    int s = (i < BSZ) ? 0 : 1;
    return feats + (size_t)(b * 2 + s) * D;
}

__device__ __forceinline__ unsigned short f2bf(float x) {  // RNE f32->bf16
    unsigned u = __builtin_bit_cast(unsigned, x);
    u = (u + 0x7FFFu + ((u >> 16) & 1u)) >> 16;
    return (unsigned short)u;
}
__device__ __forceinline__ float bf2f(unsigned short h) {
    unsigned u = ((unsigned)h) << 16;
    return __builtin_bit_cast(float, u);
}

// Panel-cooperative cvt: one block per 16-row panel. Thread slot s = w*256+tid
// maps to (k8 = s>>4, row16 = s&15) so consecutive threads write consecutive
// 16B fragment-major slots -> perfectly coalesced stores (R15's version
// scattered 16B stores at stride 256B). row16 is constant per thread, so sq
// reduces via LDS without atomics.
__global__ __launch_bounds__(256) void k_cvt(const float* __restrict__ feats,
                                             unsigned short* __restrict__ Ht,
                                             unsigned short* __restrict__ Lt,
                                             float* __restrict__ sq) {
    const int p = blockIdx.x, tid = threadIdx.x;
    const int r16 = tid & 15;
    const float* fr = feat_row(feats, p * 16 + r16);
    float p2 = 0.f;
#pragma unroll
    for (int w = 0; w < 8; ++w) {
        const int k8 = w * 16 + (tid >> 4);
        const float4 va = *(const float4*)(fr + k8 * 8);
        const float4 vb = *(const float4*)(fr + k8 * 8 + 4);
        p2 = fmaf(va.x, va.x, p2); p2 = fmaf(va.y, va.y, p2);
        p2 = fmaf(va.z, va.z, p2); p2 = fmaf(va.w, va.w, p2);
        p2 = fmaf(vb.x, vb.x, p2); p2 = fmaf(vb.y, vb.y, p2);
        p2 = fmaf(vb.z, vb.z, p2); p2 = fmaf(vb.w, vb.w, p2);
        u16x8 hv, lv;
        hv[0] = f2bf(va.x); lv[0] = f2bf(va.x - bf2f(hv[0]));
        hv[1] = f2bf(va.y); lv[1] = f2bf(va.y - bf2f(hv[1]));
        hv[2] = f2bf(va.z); lv[2] = f2bf(va.z - bf2f(hv[2]));
        hv[3] = f2bf(va.w); lv[3] = f2bf(va.w - bf2f(hv[3]));
        hv[4] = f2bf(vb.x); lv[4] = f2bf(vb.x - bf2f(hv[4]));
        hv[5] = f2bf(vb.y); lv[5] = f2bf(vb.y - bf2f(hv[5]));
        hv[6] = f2bf(vb.z); lv[6] = f2bf(vb.z - bf2f(hv[6]));
        hv[7] = f2bf(vb.w); lv[7] = f2bf(vb.w - bf2f(hv[7]));
        const size_t o = (size_t)p * PANEL + (size_t)k8 * 128 + r16 * 8;
        *(u16x8*)(Ht + o) = hv;
        *(u16x8*)(Lt + o) = lv;
    }
    __shared__ float red[16][17];
    red[tid >> 4][r16] = p2;
    __syncthreads();
    if (tid < 16) {
        float s = 0.f;
#pragma unroll
        for (int g = 0; g < 16; ++g) s += red[g][tid];
        sq[p * 16 + tid] = s;
    }
}

// Gram via MFMA on fragment-major H/L (unchanged; measured ~2.9us in R11).
__global__ __launch_bounds__(256) void k_gram(const unsigned short* __restrict__ Ht,
                                              const unsigned short* __restrict__ Lt,
                                              const float* __restrict__ sq,
                                              float* __restrict__ z) {
    int t = blockIdx.x, bi = 0;
    while (t >= NT - bi) { t -= NT - bi; ++bi; }
    const int bj = bi + t;
    const bool diag = (bi == bj);

    const int tid = threadIdx.x;
    const int lane = tid & 63, wv = tid >> 6;

    const size_t aBase = (size_t)bi * PANEL + (size_t)(wv * 32 + (lane >> 4)) * 128
                       + (size_t)(lane & 15) * 8;
    const size_t bBase = (size_t)bj * PANEL + (size_t)(wv * 32 + (lane >> 4)) * 128
                       + (size_t)(lane & 15) * 8;

    f32x4 aHH = {0.f,0.f,0.f,0.f}, aHL = {0.f,0.f,0.f,0.f}, aLH = {0.f,0.f,0.f,0.f};
#pragma unroll
    for (int s = 0; s < 8; ++s) {
        bf16x8 aH = *(const bf16x8*)(Ht + aBase + s * 512);
        bf16x8 aL = *(const bf16x8*)(Lt + aBase + s * 512);
        bf16x8 bH = *(const bf16x8*)(Ht + bBase + s * 512);
        bf16x8 bL = *(const bf16x8*)(Lt + bBase + s * 512);
        aHH = __builtin_amdgcn_mfma_f32_16x16x32_bf16(aH, bH, aHH, 0, 0, 0);
        aHL = __builtin_amdgcn_mfma_f32_16x16x32_bf16(aH, bL, aHL, 0, 0, 0);
        aLH = __builtin_amdgcn_mfma_f32_16x16x32_bf16(aL, bH, aLH, 0, 0, 0);
    }
    __shared__ f32x4 red[4][64];
    red[wv][lane] = aHH + aHL + aLH;
    __syncthreads();
    const int ls = tid & 63, r = tid >> 6;
    float g = red[0][ls][r] + red[1][ls][r] + red[2][ls][r] + red[3][ls][r];
    // C/D layout (verified): col = lane&15, row = (lane>>4)*4 + reg
    const int jj = bj * 16 + (ls & 15);
    const int ii = bi * 16 + ((ls >> 4) << 2) + r;
    if (ii != jj && (!diag || ii < jj)) {
        float sd = fmaxf(sq[ii] + sq[jj] - 2.f * g, 0.f);
        float v  = sqrtf(sd);
        z[ii * NM1 + (jj < ii ? jj : jj - 1)] = v;
        z[jj * NM1 + (ii < jj ? ii : ii - 1)] = v;
    }
}

// One block per row, 512 threads. Sort as R15 (8 waves, once). Sweep remapped:
// each WAVE owns a 48-j subrange, each LANE holds 6 k-slots in registers
// (64*6=384). LDS broadcasts per wave drop 383 -> 24 b128 + 6 slot reads
// (the measured ~15us LDS-pipe serialization term / 16).
__global__ __launch_bounds__(512) void k_main(const float* __restrict__ z,
                                              const int* __restrict__ labels,
                                              float* __restrict__ partial) {
    const int i = blockIdx.x, tid = threadIdx.x;
    const int lane = tid & 63, wv = tid >> 6;
    __shared__ float zbuf[NM1];
    __shared__ unsigned char yrow[NM1];
    __shared__ int cnt[64], startv[64], cur[64];
    __shared__ float rankd[64];
    __shared__ float2 zr[N];      // sorted (z, rank*DELTA); slot 383 = (0,0)
    __shared__ unsigned grs[N];   // lo | hi<<9 per sorted slot

    if (tid < 64) cnt[tid] = 0;
    for (int k = tid; k < NM1; k += 512) zbuf[k] = z[i * NM1 + k];
    __syncthreads();
    const int li = labels[(i < BSZ) ? i : (i - BSZ)];
    for (int k = tid; k < NM1; k += 512) {
        int col = k + (k >= i ? 1 : 0);
        int ya  = abs(li - labels[(col < BSZ) ? col : (col - BSZ)]);
        yrow[k] = (unsigned char)ya;
        atomicAdd(&cnt[ya], 1);
    }
    __syncthreads();
    if (tid < 64) {                    // wave-0 parallel exclusive scans
        const int c  = cnt[tid];
        const int nz = (c > 0) ? 1 : 0;
        int sc = c, sn = nz;
#pragma unroll
        for (int d = 1; d < 64; d <<= 1) {
            int tc = __shfl_up(sc, d);
            int tn = __shfl_up(sn, d);
            if (tid >= d) { sc += tc; sn += tn; }
        }
        startv[tid] = sc - c;
        cur[tid]    = sc - c;
        rankd[tid]  = (float)(sn - nz) * DELTA;
    }
    __syncthreads();
    for (int k = tid; k < NM1; k += 512) {
        int ya  = yrow[k];
        int pos = atomicAdd(&cur[ya], 1);
        zr[pos]  = make_float2(zbuf[k], rankd[ya]);
        grs[pos] = (unsigned)startv[ya] | ((unsigned)(startv[ya] + cnt[ya]) << 9);
    }
    if (tid == 0) { zr[NM1] = make_float2(0.f, 0.f); grs[NM1] = 0u; }
    __syncthreads();

    // 6 k-slots per lane (incl pad slot 383 at lane63/s5)
    float2 S[6];
#pragma unroll
    for (int s = 0; s < 6; ++s) S[s] = zr[lane + 64 * s];

    const int j0 = wv * 48;
    const int j1 = (j0 + 48 < NM1) ? j0 + 48 : NM1;   // wave 7: 47 j's

    float a0[6] = {0,0,0,0,0,0}, a1[6] = {0,0,0,0,0,0};
    int j = j0;
    for (; j + 2 <= j1; j += 2) {
        const float4 q = *(const float4*)&zr[j];      // j even: 16B aligned
#pragma unroll
        for (int s = 0; s < 6; ++s) {
            float tA = fabsf(S[s].x - q.x) - fabsf(S[s].y - q.y);
            a0[s] = fmaf(tA, tA, a0[s]);
            float tB = fabsf(S[s].x - q.z) - fabsf(S[s].y - q.w);
            a1[s] = fmaf(tB, tB, a1[s]);
        }
    }
    if (j < j1) {                                     // wave-7 tail (j=382)
        const float2 q = zr[j];
#pragma unroll
        for (int s = 0; s < 6; ++s) {
            float tA = fabsf(S[s].x - q.x) - fabsf(S[s].y - q.y);
            a0[s] = fmaf(tA, tA, a0[s]);
        }
    }
    float sum = 0.f;
#pragma unroll
    for (int s = 0; s < 6; ++s) sum += a0[s] + a1[s];

    // remove pad-k contribution: slot 383 swept (|0-zj|-|0-rj|)^2 = (zj-rj)^2
    // over all real j (union of the 8 subranges) -> subtract per real slot.
    if (tid < NM1) {
        float2 e = zr[tid];
        float d = e.x - e.y;
        sum = fmaf(-d, d, sum);
    }

    // correction over same-y pairs: a*sigmoid(a-DELTA) - a^2 over [lo,hi)
    if (tid < NM1) {
        const float    zj = zr[tid].x;
        const unsigned g  = grs[tid];
        const int lo = g & 0x1FF;
        const int hi = (g >> 9) & 0x1FF;
        float cs = 0.f;
        for (int k = lo; k < hi; ++k) {
            float a = fabsf(zr[k].x - zj);
            cs += a * __builtin_amdgcn_rcpf(1.f + __expf(DELTA - a)) - a * a;
        }
        sum += cs;
    }

#pragma unroll
    for (int off = 32; off; off >>= 1) sum += __shfl_xor(sum, off);
    __shared__ float part[8];
    if (lane == 0) part[wv] = sum;
    __syncthreads();
    if (tid == 0) {
        float ps = 0.f;
#pragma unroll
        for (int w = 0; w < 8; ++w) ps += part[w];
        partial[i] = ps;
    }
}

__global__ __launch_bounds__(512) void k_fin(const float* __restrict__ partial,
                                             float* __restrict__ out) {
    const int tid = threadIdx.x;
    double s = (tid < N) ? (double)partial[tid] : 0.0;
#pragma unroll
    for (int off = 32; off; off >>= 1) s += __shfl_xor(s, off);
    __shared__ double dp[8];
    if ((tid & 63) == 0) dp[tid >> 6] = s;
    __syncthreads();
    if (tid == 0) {
        double ds = 0.0;
#pragma unroll
        for (int w = 0; w < 8; ++w) ds += dp[w];
        const double M = (double)N * (double)NM1 * (double)NM1;
        out[0] = (float)(ds / M);
    }
}

extern "C" void kernel_launch(void* const* d_in, const int* in_sizes, int n_in,
                              void* d_out, int out_size, void* d_ws, size_t ws_size,
                              hipStream_t stream) {
    const float* feats  = (const float*)d_in[0];
    const int*   labels = (const int*)d_in[1];
    float*       out    = (float*)d_out;

    // ws layout (~2.2 MB total):
    char* ws = (char*)d_ws;
    float*          sq      = (float*)ws;                          // 1536 B
    float*          partial = (float*)(ws + 4096);                 // 1536 B
    unsigned short* Ht      = (unsigned short*)(ws + 16384);       // 768 KiB
    unsigned short* Lt      = (unsigned short*)(ws + 16384 + 786432);        // 768 KiB
    float*          z       = (float*)(ws + 16384 + 2 * 786432);   // 588 KiB

    k_cvt <<<NT, 256, 0, stream>>>(feats, Ht, Lt, sq);
    k_gram<<<NTILES, 256, 0, stream>>>(Ht, Lt, sq, z);
    k_main<<<N, 512, 0, stream>>>(z, labels, partial);
    k_fin <<<1, 512, 0, stream>>>(partial, out);
}